// Round 7
// baseline (428.505 us; speedup 1.0000x reference)
//
#include <hip/hip_runtime.h>

#define N_NODES 100000
#define D 128
#define R_REL 4
#define E_EDGES 150000
#define M_SEG (R_REL * N_NODES)          // 400000 segments (r, dst)
#define NSEG 5                           // 4 relations + self-loop
#define CAP 16                           // fixed bin capacity per segment

typedef short short8 __attribute__((ext_vector_type(8)));
typedef float f32x4 __attribute__((ext_vector_type(4)));

// round-to-nearest-even float -> bf16 bits
__device__ __forceinline__ unsigned short f2bf(float f) {
    unsigned u = __float_as_uint(f);
    return (unsigned short)((u + 0x7fffu + ((u >> 16) & 1u)) >> 16);
}
__device__ __forceinline__ void splitbf(float f, unsigned short& hi, unsigned short& lo) {
    unsigned short h = f2bf(f);
    float fh = __uint_as_float(((unsigned)h) << 16);
    lo = f2bf(f - fh);
    hi = h;
}

// ---------------------------------------------------------------------------
// Combined prep kernel. Blocks [0, EB): one-pass edge binning
// (cnt[seg] in-degree count; epool[seg*CAP+pos]=src). Blocks [EB, EB+BB):
// B pre-convert to bf16 hi/lo in MFMA-fragment order [seg][ks][tile][lane][8].
// ---------------------------------------------------------------------------
#define EB ((R_REL * E_EDGES + 255) / 256)
#define BCONV_N (NSEG * 4 * 8 * 64 * 8)
#define BB ((BCONV_N + 255) / 256)

__global__ __launch_bounds__(256) void prep_kernel(
    const int* __restrict__ src_idx, const int* __restrict__ dst_idx,
    const float* __restrict__ rel_w, const float* __restrict__ loop_w,
    int* __restrict__ cnt, int* __restrict__ epool,
    unsigned short* __restrict__ bhi, unsigned short* __restrict__ blo)
{
    if (blockIdx.x < EB) {
        int idx = blockIdx.x * 256 + threadIdx.x;
        if (idx >= R_REL * E_EDGES) return;
        int r = idx / E_EDGES;
        int i = r * N_NODES + dst_idx[idx];
        int pos = atomicAdd(&cnt[i], 1);
        if (pos < CAP) epool[(size_t)i * CAP + pos] = src_idx[idx];
    } else {
        int idx = (blockIdx.x - EB) * 256 + threadIdx.x;
        if (idx >= BCONV_N) return;
        int j   = idx & 7;
        int l   = (idx >> 3) & 63;
        int t   = (idx >> 9) & 7;
        int ks  = (idx >> 12) & 3;
        int seg = idx >> 14;
        int k   = ks * 32 + (l >> 4) * 8 + j;
        int col = t * 16 + (l & 15);
        float v = (seg < R_REL) ? rel_w[((size_t)seg * D + k) * D + col]
                                : loop_w[(size_t)k * D + col];
        unsigned short h, lo;
        splitbf(v, h, lo);
        bhi[idx] = h;
        blo[idx] = lo;
    }
}

// ---------------------------------------------------------------------------
// Fused gather + split-bf16 MFMA GEMM.
// Block: 64 rows x 128 cols, 256 threads (4 waves). Gather per half-wave
// group (8 rows): ONE upfront int4 index load per row (j=0..3 covers 98% of
// rows), then x-row loads software-pipelined across j with double-buffered
// batches (16 outstanding loads). Rare deg>4 tail uses the scalar path.
// ---------------------------------------------------------------------------
__global__ __launch_bounds__(256) void fused_gemm_kernel(
    const float* __restrict__ x,
    const int* __restrict__ cnt,
    const int* __restrict__ epool,
    const unsigned short* __restrict__ bhi,
    const unsigned short* __restrict__ blo,
    const float* __restrict__ bias,
    float* __restrict__ out)
{
    __shared__ unsigned short AsHi[64 * 128];   // 16 KB, swizzled
    __shared__ unsigned short AsLo[64 * 128];   // 16 KB, swizzled

    int tid = threadIdx.x;
    int w = tid >> 6;                   // wave 0..3
    int l = tid & 63;                   // lane
    int g = tid >> 5;                   // half-wave group 0..7 (8 rows each)
    int tx = tid & 31;                  // lane in group: float4 col chunk
    int n0 = blockIdx.x * 64;

    f32x4 acc[8];
    #pragma unroll
    for (int t = 0; t < 8; t++) acc[t] = (f32x4){0.f, 0.f, 0.f, 0.f};

    const float4* x4 = (const float4*)x;
    const int4* ep4 = (const int4*)epool;

    for (int seg = 0; seg < NSEG; seg++) {
        __syncthreads();                // protect As from previous segment's reads

        if (seg < R_REL) {
            // ---- per-row metadata (8 cnt loads in flight) ----
            int dg[8], dgc[8], pb[8];
            #pragma unroll
            for (int i = 0; i < 8; i++) {
                int n = n0 + g * 8 + i;
                int sid = seg * N_NODES + min(n, N_NODES - 1);
                int c = (n < N_NODES) ? cnt[sid] : 0;
                dg[i] = c;
                dgc[i] = min(c, CAP);
                pb[i] = sid * CAP;
            }
            // ---- upfront indices: one int4 per row, 8 loads in flight ----
            int4 idx4[8];
            #pragma unroll
            for (int i = 0; i < 8; i++)
                idx4[i] = ep4[pb[i] >> 2];          // bin start, 16B aligned

            float4 a[8];
            #pragma unroll
            for (int i = 0; i < 8; i++) a[i] = make_float4(0.f, 0.f, 0.f, 0.f);

            // ---- software-pipelined j=0..3, double-buffered ----
            float4 vA[8], vB[8];
            #pragma unroll
            for (int i = 0; i < 8; i++) {           // issue j=0
                bool live = 0 < dgc[i];
                int ss = live ? idx4[i].x : 0;
                vA[i] = x4[(size_t)ss * 32 + tx];
            }
            #pragma unroll
            for (int i = 0; i < 8; i++) {           // issue j=1
                bool live = 1 < dgc[i];
                int ss = live ? idx4[i].y : 0;
                vB[i] = x4[(size_t)ss * 32 + tx];
            }
            #pragma unroll
            for (int i = 0; i < 8; i++) {           // accum j=0 (waits vA only)
                float mk = (0 < dgc[i]) ? 1.f : 0.f;
                a[i].x += vA[i].x * mk; a[i].y += vA[i].y * mk;
                a[i].z += vA[i].z * mk; a[i].w += vA[i].w * mk;
            }
            #pragma unroll
            for (int i = 0; i < 8; i++) {           // issue j=2
                bool live = 2 < dgc[i];
                int ss = live ? idx4[i].z : 0;
                vA[i] = x4[(size_t)ss * 32 + tx];
            }
            #pragma unroll
            for (int i = 0; i < 8; i++) {           // accum j=1
                float mk = (1 < dgc[i]) ? 1.f : 0.f;
                a[i].x += vB[i].x * mk; a[i].y += vB[i].y * mk;
                a[i].z += vB[i].z * mk; a[i].w += vB[i].w * mk;
            }
            #pragma unroll
            for (int i = 0; i < 8; i++) {           // issue j=3
                bool live = 3 < dgc[i];
                int ss = live ? idx4[i].w : 0;
                vB[i] = x4[(size_t)ss * 32 + tx];
            }
            #pragma unroll
            for (int i = 0; i < 8; i++) {           // accum j=2
                float mk = (2 < dgc[i]) ? 1.f : 0.f;
                a[i].x += vA[i].x * mk; a[i].y += vA[i].y * mk;
                a[i].z += vA[i].z * mk; a[i].w += vA[i].w * mk;
            }
            #pragma unroll
            for (int i = 0; i < 8; i++) {           // accum j=3
                float mk = (3 < dgc[i]) ? 1.f : 0.f;
                a[i].x += vB[i].x * mk; a[i].y += vB[i].y * mk;
                a[i].z += vB[i].z * mk; a[i].w += vB[i].w * mk;
            }

            // ---- rare tail: deg > 4 (P ≈ 1.9% per row) ----
            int md = 0;
            #pragma unroll
            for (int i = 0; i < 8; i++) md = max(md, dgc[i]);
            for (int j = 4; j < md; j++) {
                int sn[8];
                #pragma unroll
                for (int i = 0; i < 8; i++)
                    sn[i] = epool[pb[i] + min(j, dgc[i] - 1 > 0 ? dgc[i] - 1 : 0)];
                #pragma unroll
                for (int i = 0; i < 8; i++) {
                    bool live = j < dgc[i];
                    int ss = live ? sn[i] : 0;
                    float mk = live ? 1.f : 0.f;
                    float4 v = x4[(size_t)ss * 32 + tx];
                    a[i].x += v.x * mk; a[i].y += v.y * mk;
                    a[i].z += v.z * mk; a[i].w += v.w * mk;
                }
            }

            // ---- normalize, split, stage to LDS (swizzled) ----
            #pragma unroll
            for (int i = 0; i < 8; i++) {
                int row = g * 8 + i;
                float sc = 1.0f / fmaxf((float)dg[i], 1.0f);
                float vv[4] = {a[i].x * sc, a[i].y * sc, a[i].z * sc, a[i].w * sc};
                unsigned short h[4], lo[4];
                #pragma unroll
                for (int c = 0; c < 4; c++) splitbf(vv[c], h[c], lo[c]);
                uint2 ph = make_uint2((unsigned)h[0] | ((unsigned)h[1] << 16),
                                      (unsigned)h[2] | ((unsigned)h[3] << 16));
                uint2 pl = make_uint2((unsigned)lo[0] | ((unsigned)lo[1] << 16),
                                      (unsigned)lo[2] | ((unsigned)lo[3] << 16));
                int boff = row * 256 + ((tx * 8) ^ ((row & 7) << 4));
                *(uint2*)((char*)AsHi + boff) = ph;
                *(uint2*)((char*)AsLo + boff) = pl;
            }
        } else {
            // ---- self-loop staging ----
            #pragma unroll
            for (int i = 0; i < 8; i++) {
                int row = g * 8 + i;
                int n = n0 + row;
                float4 v = make_float4(0.f, 0.f, 0.f, 0.f);
                if (n < N_NODES) v = x4[(size_t)n * 32 + tx];
                float vv[4] = {v.x, v.y, v.z, v.w};
                unsigned short h[4], lo[4];
                #pragma unroll
                for (int c = 0; c < 4; c++) splitbf(vv[c], h[c], lo[c]);
                uint2 ph = make_uint2((unsigned)h[0] | ((unsigned)h[1] << 16),
                                      (unsigned)h[2] | ((unsigned)h[3] << 16));
                uint2 pl = make_uint2((unsigned)lo[0] | ((unsigned)lo[1] << 16),
                                      (unsigned)lo[2] | ((unsigned)lo[3] << 16));
                int boff = row * 256 + ((tx * 8) ^ ((row & 7) << 4));
                *(uint2*)((char*)AsHi + boff) = ph;
                *(uint2*)((char*)AsLo + boff) = pl;
            }
        }
        __syncthreads();

        // ---- MFMA: wave w, rows w*16..w*16+15, 4 k-steps of 32 ----
        #pragma unroll
        for (int ks = 0; ks < 4; ks++) {
            int row = w * 16 + (l & 15);
            int cbyte = (ks * 64 + ((l >> 4) << 4)) ^ ((row & 7) << 4);
            short8 aHi = *(const short8*)((const char*)AsHi + row * 256 + cbyte);
            short8 aLo = *(const short8*)((const char*)AsLo + row * 256 + cbyte);
            size_t fb = ((((size_t)seg * 4 + ks) * 8) * 64 + l) * 8;
            #pragma unroll
            for (int t = 0; t < 8; t++) {
                short8 bH = *(const short8*)(bhi + fb + (size_t)t * 512);
                short8 bL = *(const short8*)(blo + fb + (size_t)t * 512);
                acc[t] = __builtin_amdgcn_mfma_f32_16x16x32_bf16(aHi, bH, acc[t], 0, 0, 0);
                acc[t] = __builtin_amdgcn_mfma_f32_16x16x32_bf16(aHi, bL, acc[t], 0, 0, 0);
                acc[t] = __builtin_amdgcn_mfma_f32_16x16x32_bf16(aLo, bH, acc[t], 0, 0, 0);
            }
        }
    }

    // ---- epilogue: C/D layout col = l&15, row = (l>>4)*4 + reg ----
    int rbase = n0 + w * 16 + ((l >> 4) << 2);
    int cl = l & 15;
    #pragma unroll
    for (int t = 0; t < 8; t++) {
        float bv = bias[t * 16 + cl];
        #pragma unroll
        for (int reg = 0; reg < 4; reg++) {
            int n = rbase + reg;
            if (n < N_NODES)
                out[(size_t)n * D + t * 16 + cl] = fmaxf(acc[t][reg] + bv, 0.f);
        }
    }
}

extern "C" void kernel_launch(void* const* d_in, const int* in_sizes, int n_in,
                              void* d_out, int out_size, void* d_ws, size_t ws_size,
                              hipStream_t stream)
{
    const float* x      = (const float*)d_in[0];
    const int*   src    = (const int*)d_in[1];
    const int*   dst    = (const int*)d_in[2];
    const float* rel_w  = (const float*)d_in[3];
    const float* loop_w = (const float*)d_in[4];
    const float* bias   = (const float*)d_in[5];
    float* out = (float*)d_out;

    // ws layout: cnt[M_SEG] | epool[M_SEG*CAP] | bhi | blo
    int* cnt   = (int*)d_ws;
    int* epool = cnt + M_SEG;
    unsigned short* bhi = (unsigned short*)(epool + (size_t)M_SEG * CAP);
    unsigned short* blo = bhi + (size_t)BCONV_N;

    hipMemsetAsync(cnt, 0, (size_t)M_SEG * sizeof(int), stream);

    prep_kernel<<<EB + BB, 256, 0, stream>>>(src, dst, rel_w, loop_w,
                                             cnt, epool, bhi, blo);

    int mblocks = (N_NODES + 63) / 64;
    fused_gemm_kernel<<<mblocks, 256, 0, stream>>>(x, cnt, epool, bhi, blo,
                                                   bias, out);
}

// Round 8
// 370.813 us; speedup vs baseline: 1.1556x; 1.1556x over previous
//
#include <hip/hip_runtime.h>

#define N_NODES 100000
#define D 128
#define R_REL 4
#define E_EDGES 150000
#define M_SEG (R_REL * N_NODES)          // 400000 segments (r, dst)
#define NSEG 5                           // 4 relations + self-loop
#define CAP 16                           // fixed bin capacity per segment

typedef short short8 __attribute__((ext_vector_type(8)));
typedef float f32x4 __attribute__((ext_vector_type(4)));

// round-to-nearest-even float -> bf16 bits
__device__ __forceinline__ unsigned short f2bf(float f) {
    unsigned u = __float_as_uint(f);
    return (unsigned short)((u + 0x7fffu + ((u >> 16) & 1u)) >> 16);
}
__device__ __forceinline__ void splitbf(float f, unsigned short& hi, unsigned short& lo) {
    unsigned short h = f2bf(f);
    float fh = __uint_as_float(((unsigned)h) << 16);
    lo = f2bf(f - fh);
    hi = h;
}

// ---------------------------------------------------------------------------
// Prep: blocks [0,EB) do one-pass edge binning (cnt = in-degree,
// epool[seg*CAP+pos] = src). Blocks [EB,EB+BB) pre-convert W to bf16 hi/lo
// in MFMA B-fragment order [seg][ks][t][lane][8] (lane l: col=t*16+(l&15),
// k = ks*32 + (l>>4)*8 + j).
// ---------------------------------------------------------------------------
#define EB ((R_REL * E_EDGES + 255) / 256)
#define BCONV_N (NSEG * 4 * 8 * 64 * 8)
#define BB ((BCONV_N + 255) / 256)

__global__ __launch_bounds__(256) void prep_kernel(
    const int* __restrict__ src_idx, const int* __restrict__ dst_idx,
    const float* __restrict__ rel_w, const float* __restrict__ loop_w,
    int* __restrict__ cnt, int* __restrict__ epool,
    unsigned short* __restrict__ bhi, unsigned short* __restrict__ blo)
{
    if (blockIdx.x < EB) {
        int idx = blockIdx.x * 256 + threadIdx.x;
        if (idx >= R_REL * E_EDGES) return;
        int r = idx / E_EDGES;
        int i = r * N_NODES + dst_idx[idx];
        int pos = atomicAdd(&cnt[i], 1);
        if (pos < CAP) epool[(size_t)i * CAP + pos] = src_idx[idx];
    } else {
        int idx = (blockIdx.x - EB) * 256 + threadIdx.x;
        if (idx >= BCONV_N) return;
        int j   = idx & 7;
        int l   = (idx >> 3) & 63;
        int t   = (idx >> 9) & 7;
        int ks  = (idx >> 12) & 3;
        int seg = idx >> 14;
        int k   = ks * 32 + (l >> 4) * 8 + j;
        int col = t * 16 + (l & 15);
        float v = (seg < R_REL) ? rel_w[((size_t)seg * D + k) * D + col]
                                : loop_w[(size_t)k * D + col];
        unsigned short h, lo;
        splitbf(v, h, lo);
        bhi[idx] = h;
        blo[idx] = lo;
    }
}

// ---------------------------------------------------------------------------
// Dense streaming GEMM: Z_s = X @ W_s for segs [seg0, seg0+nseg_c).
// Block: 64 x-rows, 256 threads (4 waves). x staged ONCE as swizzled bf16
// hi/lo; A-fragments hoisted to registers; per segment 32 MFMAs/wave
// (split-precision: AhBh + AhBl + AlBh), raw fp32 Z written.
// ---------------------------------------------------------------------------
__global__ __launch_bounds__(256) void gemmz_kernel(
    const float* __restrict__ x,
    const unsigned short* __restrict__ bhi,
    const unsigned short* __restrict__ blo,
    float* __restrict__ z,              // [nseg_c][N][D]
    int seg0, int nseg_c)
{
    __shared__ unsigned short AsHi[64 * 128];   // 16 KB, swizzled
    __shared__ unsigned short AsLo[64 * 128];   // 16 KB, swizzled

    int tid = threadIdx.x;
    int w = tid >> 6;                   // wave 0..3
    int l = tid & 63;                   // lane
    int g = tid >> 5;                   // half-wave group 0..7
    int tx = tid & 31;                  // lane in group
    int n0 = blockIdx.x * 64;

    const float4* x4 = (const float4*)x;

    // ---- stage x-tile (rows n0..n0+63), split hi/lo, swizzled ----
    #pragma unroll
    for (int i = 0; i < 8; i++) {
        int row = g * 8 + i;
        int n = n0 + row;
        float4 v = make_float4(0.f, 0.f, 0.f, 0.f);
        if (n < N_NODES) v = x4[(size_t)n * 32 + tx];
        float vv[4] = {v.x, v.y, v.z, v.w};
        unsigned short h[4], lo[4];
        #pragma unroll
        for (int c = 0; c < 4; c++) splitbf(vv[c], h[c], lo[c]);
        uint2 ph = make_uint2((unsigned)h[0] | ((unsigned)h[1] << 16),
                              (unsigned)h[2] | ((unsigned)h[3] << 16));
        uint2 pl = make_uint2((unsigned)lo[0] | ((unsigned)lo[1] << 16),
                              (unsigned)lo[2] | ((unsigned)lo[3] << 16));
        int boff = row * 256 + ((tx * 8) ^ ((row & 7) << 4));
        *(uint2*)((char*)AsHi + boff) = ph;
        *(uint2*)((char*)AsLo + boff) = pl;
    }
    __syncthreads();

    // ---- hoist A-fragments (reused across all segments) ----
    int arow = w * 16 + (l & 15);
    short8 aH[4], aL[4];
    #pragma unroll
    for (int ks = 0; ks < 4; ks++) {
        int cbyte = (ks * 64 + ((l >> 4) << 4)) ^ ((arow & 7) << 4);
        aH[ks] = *(const short8*)((const char*)AsHi + arow * 256 + cbyte);
        aL[ks] = *(const short8*)((const char*)AsLo + arow * 256 + cbyte);
    }

    int rbase = n0 + w * 16 + ((l >> 4) << 2);
    int cl = l & 15;

    for (int sc = 0; sc < nseg_c; sc++) {
        int seg = seg0 + sc;
        f32x4 acc[8];
        #pragma unroll
        for (int t = 0; t < 8; t++) acc[t] = (f32x4){0.f, 0.f, 0.f, 0.f};

        #pragma unroll
        for (int ks = 0; ks < 4; ks++) {
            size_t fb = ((((size_t)seg * 4 + ks) * 8) * 64 + l) * 8;
            #pragma unroll
            for (int t = 0; t < 8; t++) {
                short8 bH = *(const short8*)(bhi + fb + (size_t)t * 512);
                short8 bL = *(const short8*)(blo + fb + (size_t)t * 512);
                acc[t] = __builtin_amdgcn_mfma_f32_16x16x32_bf16(aH[ks], bH, acc[t], 0, 0, 0);
                acc[t] = __builtin_amdgcn_mfma_f32_16x16x32_bf16(aH[ks], bL, acc[t], 0, 0, 0);
                acc[t] = __builtin_amdgcn_mfma_f32_16x16x32_bf16(aL[ks], bH, acc[t], 0, 0, 0);
            }
        }

        // ---- write raw Z (C/D layout: col=l&15, row=(l>>4)*4+reg) ----
        float* zp = z + (size_t)sc * N_NODES * D;
        #pragma unroll
        for (int t = 0; t < 8; t++) {
            #pragma unroll
            for (int reg = 0; reg < 4; reg++) {
                int n = rbase + reg;
                if (n < N_NODES)
                    zp[(size_t)n * D + t * 16 + cl] = acc[t][reg];
            }
        }
    }
}

// ---------------------------------------------------------------------------
// High-TLP combine: 32 lanes per node (float4/lane = 128 cols), 3.2M threads.
// For each relation seg in chunk: gather Z_s rows of in-edges, masked-sum,
// /deg. Loop seg adds Z directly. Accumulates into out across chunks;
// final chunk adds bias + relu.
// ---------------------------------------------------------------------------
__global__ __launch_bounds__(256) void aggk_kernel(
    const float* __restrict__ z,        // [nseg_c][N][D]
    const int* __restrict__ cnt,
    const int* __restrict__ epool,
    const float* __restrict__ bias,
    float* __restrict__ out,
    int seg0, int nseg_c, int flags)    // bit0 = first chunk, bit1 = last
{
    int idx = blockIdx.x * 256 + threadIdx.x;
    int n = idx >> 5;
    int lane = idx & 31;
    if (n >= N_NODES) return;

    const float4* z4 = (const float4*)z;
    const int4* ep4 = (const int4*)epool;

    float4 acc;
    if (flags & 1) acc = make_float4(0.f, 0.f, 0.f, 0.f);
    else           acc = ((const float4*)(out + (size_t)n * D))[lane];

    for (int sc = 0; sc < nseg_c; sc++) {
        int seg = seg0 + sc;
        size_t zb = (size_t)sc * N_NODES * 32;      // float4 units per plane
        if (seg < R_REL) {
            int sid = seg * N_NODES + n;
            int c = cnt[sid];
            int cc = min(c, CAP);
            int4 i4 = ep4[sid * (CAP / 4)];         // first 4 indices
            float4 s = make_float4(0.f, 0.f, 0.f, 0.f);
            // 4 independent masked loads (covers 98% of rows)
            int s0 = (0 < cc) ? i4.x : 0;  float m0 = (0 < cc) ? 1.f : 0.f;
            int s1 = (1 < cc) ? i4.y : 0;  float m1 = (1 < cc) ? 1.f : 0.f;
            int s2 = (2 < cc) ? i4.z : 0;  float m2 = (2 < cc) ? 1.f : 0.f;
            int s3 = (3 < cc) ? i4.w : 0;  float m3 = (3 < cc) ? 1.f : 0.f;
            float4 v0 = z4[zb + (size_t)s0 * 32 + lane];
            float4 v1 = z4[zb + (size_t)s1 * 32 + lane];
            float4 v2 = z4[zb + (size_t)s2 * 32 + lane];
            float4 v3 = z4[zb + (size_t)s3 * 32 + lane];
            s.x = v0.x * m0 + v1.x * m1 + v2.x * m2 + v3.x * m3;
            s.y = v0.y * m0 + v1.y * m1 + v2.y * m2 + v3.y * m3;
            s.z = v0.z * m0 + v1.z * m1 + v2.z * m2 + v3.z * m3;
            s.w = v0.w * m0 + v1.w * m1 + v2.w * m2 + v3.w * m3;
            // rare tail (deg > 4)
            for (int j = 4; j < cc; j++) {
                int sj = epool[(size_t)sid * CAP + j];
                float4 v = z4[zb + (size_t)sj * 32 + lane];
                s.x += v.x; s.y += v.y; s.z += v.z; s.w += v.w;
            }
            float sc_n = 1.0f / fmaxf((float)c, 1.0f);
            acc.x += s.x * sc_n; acc.y += s.y * sc_n;
            acc.z += s.z * sc_n; acc.w += s.w * sc_n;
        } else {
            // self-loop: direct read
            float4 v = z4[zb + (size_t)n * 32 + lane];
            acc.x += v.x; acc.y += v.y; acc.z += v.z; acc.w += v.w;
        }
    }

    if (flags & 2) {
        float4 bv = ((const float4*)bias)[lane];
        acc.x = fmaxf(acc.x + bv.x, 0.f);
        acc.y = fmaxf(acc.y + bv.y, 0.f);
        acc.z = fmaxf(acc.z + bv.z, 0.f);
        acc.w = fmaxf(acc.w + bv.w, 0.f);
    }
    ((float4*)(out + (size_t)n * D))[lane] = acc;
}

extern "C" void kernel_launch(void* const* d_in, const int* in_sizes, int n_in,
                              void* d_out, int out_size, void* d_ws, size_t ws_size,
                              hipStream_t stream)
{
    const float* x      = (const float*)d_in[0];
    const int*   src    = (const int*)d_in[1];
    const int*   dst    = (const int*)d_in[2];
    const float* rel_w  = (const float*)d_in[3];
    const float* loop_w = (const float*)d_in[4];
    const float* bias   = (const float*)d_in[5];
    float* out = (float*)d_out;

    // ws layout: cnt[M_SEG] | epool[M_SEG*CAP] | bhi | blo | align | z
    int* cnt   = (int*)d_ws;
    int* epool = cnt + M_SEG;
    unsigned short* bhi = (unsigned short*)(epool + (size_t)M_SEG * CAP);
    unsigned short* blo = bhi + (size_t)BCONV_N;
    size_t zoff = ((size_t)M_SEG * 4 + (size_t)M_SEG * CAP * 4 +
                   (size_t)BCONV_N * 4 + 255) & ~(size_t)255;
    float* z = (float*)((char*)d_ws + zoff);

    const size_t plane_bytes = (size_t)N_NODES * D * sizeof(float);
    size_t avail = (ws_size > zoff) ? (ws_size - zoff) : 0;
    int spc = (int)(avail / plane_bytes);           // seg planes per chunk
    if (spc < 1) spc = 1;                           // (ws evidence: >=206 MB)
    if (spc > NSEG) spc = NSEG;

    hipMemsetAsync(cnt, 0, (size_t)M_SEG * sizeof(int), stream);
    prep_kernel<<<EB + BB, 256, 0, stream>>>(src, dst, rel_w, loop_w,
                                             cnt, epool, bhi, blo);

    const int gblocks = (N_NODES + 63) / 64;
    const int ablocks = (N_NODES * 32 + 255) / 256;

    int done = 0;
    int first = 1;
    while (done < NSEG) {
        int take = NSEG - done;
        if (take > spc) take = spc;
        int last = (done + take == NSEG);
        gemmz_kernel<<<gblocks, 256, 0, stream>>>(x, bhi, blo, z, done, take);
        aggk_kernel<<<ablocks, 256, 0, stream>>>(z, cnt, epool, bias, out,
                                                 done, take,
                                                 (first ? 1 : 0) | (last ? 2 : 0));
        done += take;
        first = 0;
    }
}

// Round 9
// 260.855 us; speedup vs baseline: 1.6427x; 1.4215x over previous
//
#include <hip/hip_runtime.h>

#define N_NODES 100000
#define D 128
#define R_REL 4
#define E_EDGES 150000
#define M_SEG (R_REL * N_NODES)          // 400000 segments (r, dst)
#define NSEG 5                           // 4 relations + self-loop
#define CAP 16                           // fixed bin capacity per segment

typedef _Float16 half8v __attribute__((ext_vector_type(8)));
typedef _Float16 half4v __attribute__((ext_vector_type(4)));
typedef float f32x4 __attribute__((ext_vector_type(4)));

// ---------------------------------------------------------------------------
// Prep: blocks [0,EB): one-pass edge binning (cnt = in-degree,
// epool[seg*CAP+pos] = src). Blocks [EB,EB+BB): W -> fp16 in MFMA B-fragment
// order [seg][ks][t][lane][8] (lane l: col=t*16+(l&15), k=ks*32+(l>>4)*8+j).
// ---------------------------------------------------------------------------
#define EB ((R_REL * E_EDGES + 255) / 256)
#define BCONV_N (NSEG * 4 * 8 * 64 * 8)
#define BB ((BCONV_N + 255) / 256)

__global__ __launch_bounds__(256) void prep_kernel(
    const int* __restrict__ src_idx, const int* __restrict__ dst_idx,
    const float* __restrict__ rel_w, const float* __restrict__ loop_w,
    int* __restrict__ cnt, int* __restrict__ epool,
    _Float16* __restrict__ bh)
{
    if (blockIdx.x < EB) {
        int idx = blockIdx.x * 256 + threadIdx.x;
        if (idx >= R_REL * E_EDGES) return;
        int r = idx / E_EDGES;
        int i = r * N_NODES + dst_idx[idx];
        int pos = atomicAdd(&cnt[i], 1);
        if (pos < CAP) epool[(size_t)i * CAP + pos] = src_idx[idx];
    } else {
        int idx = (blockIdx.x - EB) * 256 + threadIdx.x;
        if (idx >= BCONV_N) return;
        int j   = idx & 7;
        int l   = (idx >> 3) & 63;
        int t   = (idx >> 9) & 7;
        int ks  = (idx >> 12) & 3;
        int seg = idx >> 14;
        int k   = ks * 32 + (l >> 4) * 8 + j;
        int col = t * 16 + (l & 15);
        float v = (seg < R_REL) ? rel_w[((size_t)seg * D + k) * D + col]
                                : loop_w[(size_t)k * D + col];
        bh[idx] = (_Float16)v;
    }
}

// ---------------------------------------------------------------------------
// Dense GEMM, single-pass fp16 MFMA: Z_s = X @ W_s for all 5 segments.
// Block: 64 x-rows, 256 threads (4 waves). x staged once (fp16, XOR-swizzled,
// pitch 256B); A-fragments hoisted to registers; 32 MFMAs/wave/segment.
// Epilogue: acc -> LDS (pitch 272B) -> coalesced float4 stores of fp16 Z.
// ---------------------------------------------------------------------------
__global__ __launch_bounds__(256) void gemmz_kernel(
    const float* __restrict__ x,
    const _Float16* __restrict__ bh,
    _Float16* __restrict__ z)           // [NSEG][N][D] fp16
{
    __shared__ __align__(16) char lds[64 * 272];   // 17 KB, dual-purpose

    int tid = threadIdx.x;
    int w = tid >> 6;                   // wave 0..3
    int l = tid & 63;                   // lane
    int g = tid >> 5;                   // half-wave group 0..7
    int tx = tid & 31;                  // lane in group
    int n0 = blockIdx.x * 64;

    const float4* x4 = (const float4*)x;

    // ---- stage x-tile as fp16, swizzled, pitch 256B ----
    #pragma unroll
    for (int i = 0; i < 8; i++) {
        int row = g * 8 + i;
        int n = n0 + row;
        float4 v = make_float4(0.f, 0.f, 0.f, 0.f);
        if (n < N_NODES) v = x4[(size_t)n * 32 + tx];
        half4v hv = {(_Float16)v.x, (_Float16)v.y, (_Float16)v.z, (_Float16)v.w};
        int boff = row * 256 + ((tx * 8) ^ ((row & 7) << 4));
        *(half4v*)(lds + boff) = hv;
    }
    __syncthreads();

    // ---- hoist A-fragments (reused across all 5 segments) ----
    int arow = w * 16 + (l & 15);
    half8v aF[4];
    #pragma unroll
    for (int ks = 0; ks < 4; ks++) {
        int cbyte = (ks * 64 + ((l >> 4) << 4)) ^ ((arow & 7) << 4);
        aF[ks] = *(const half8v*)(lds + arow * 256 + cbyte);
    }
    __syncthreads();                    // As dead; lds reused by epilogue

    int cl = l & 15;
    int lrow0 = w * 16 + ((l >> 4) << 2);   // local row of acc reg 0

    for (int seg = 0; seg < NSEG; seg++) {
        f32x4 acc[8];
        #pragma unroll
        for (int t = 0; t < 8; t++) acc[t] = (f32x4){0.f, 0.f, 0.f, 0.f};

        #pragma unroll
        for (int ks = 0; ks < 4; ks++) {
            size_t fb = ((((size_t)seg * 4 + ks) * 8) * 64 + l) * 8;
            #pragma unroll
            for (int t = 0; t < 8; t++) {
                half8v bF = *(const half8v*)(bh + fb + (size_t)t * 512);
                acc[t] = __builtin_amdgcn_mfma_f32_16x16x32_f16(aF[ks], bF, acc[t], 0, 0, 0);
            }
        }

        // ---- epilogue: acc -> LDS (fp16, pitch 272B) ----
        #pragma unroll
        for (int t = 0; t < 8; t++) {
            #pragma unroll
            for (int reg = 0; reg < 4; reg++) {
                int lrow = lrow0 + reg;
                ((_Float16*)(lds + lrow * 272))[t * 16 + cl] = (_Float16)acc[t][reg];
            }
        }
        __syncthreads();

        // ---- coalesced store: 4 passes, 16B/lane, rows contiguous ----
        _Float16* zp = z + (size_t)seg * N_NODES * D;
        #pragma unroll
        for (int p = 0; p < 4; p++) {
            int row = p * 16 + (tid >> 4);
            int s = tid & 15;
            float4 rv = *(const float4*)(lds + row * 272 + s * 16);
            int n = n0 + row;
            if (n < N_NODES)
                *(float4*)((char*)(zp + (size_t)n * D) + s * 16) = rv;
        }
        __syncthreads();                // protect lds for next segment
    }
}

// ---------------------------------------------------------------------------
// High-TLP combine: 32 lanes/node (4 cols each), 3.2M threads. Per relation:
// gather fp16 Z rows of in-edges (4 masked loads cover 98% of rows), /deg.
// Self-loop plane added directly; bias + relu; fp32 out.
// ---------------------------------------------------------------------------
__global__ __launch_bounds__(256) void aggk_kernel(
    const _Float16* __restrict__ z,     // [NSEG][N][D]
    const int* __restrict__ cnt,
    const int* __restrict__ epool,
    const float* __restrict__ bias,
    float* __restrict__ out)
{
    int idx = blockIdx.x * 256 + threadIdx.x;
    int n = idx >> 5;
    int lane = idx & 31;
    if (n >= N_NODES) return;

    const int4* ep4 = (const int4*)epool;
    float ax = 0.f, ay = 0.f, az = 0.f, aw = 0.f;

    for (int seg = 0; seg < R_REL; seg++) {
        int sid = seg * N_NODES + n;
        int c = cnt[sid];
        int cc = min(c, CAP);
        int4 i4 = ep4[(size_t)sid * (CAP / 4)];
        const _Float16* zp = z + (size_t)seg * N_NODES * D;

        int s0 = (0 < cc) ? i4.x : 0;  float m0 = (0 < cc) ? 1.f : 0.f;
        int s1 = (1 < cc) ? i4.y : 0;  float m1 = (1 < cc) ? 1.f : 0.f;
        int s2 = (2 < cc) ? i4.z : 0;  float m2 = (2 < cc) ? 1.f : 0.f;
        int s3 = (3 < cc) ? i4.w : 0;  float m3 = (3 < cc) ? 1.f : 0.f;
        half4v v0 = *(const half4v*)(zp + (size_t)s0 * D + lane * 4);
        half4v v1 = *(const half4v*)(zp + (size_t)s1 * D + lane * 4);
        half4v v2 = *(const half4v*)(zp + (size_t)s2 * D + lane * 4);
        half4v v3 = *(const half4v*)(zp + (size_t)s3 * D + lane * 4);

        float sx = (float)v0[0]*m0 + (float)v1[0]*m1 + (float)v2[0]*m2 + (float)v3[0]*m3;
        float sy = (float)v0[1]*m0 + (float)v1[1]*m1 + (float)v2[1]*m2 + (float)v3[1]*m3;
        float sz = (float)v0[2]*m0 + (float)v1[2]*m1 + (float)v2[2]*m2 + (float)v3[2]*m3;
        float sw = (float)v0[3]*m0 + (float)v1[3]*m1 + (float)v2[3]*m2 + (float)v3[3]*m3;

        for (int j = 4; j < cc; j++) {
            int sj = epool[(size_t)sid * CAP + j];
            half4v v = *(const half4v*)(zp + (size_t)sj * D + lane * 4);
            sx += (float)v[0]; sy += (float)v[1];
            sz += (float)v[2]; sw += (float)v[3];
        }
        float sc = 1.0f / fmaxf((float)c, 1.0f);
        ax += sx * sc; ay += sy * sc; az += sz * sc; aw += sw * sc;
    }

    // self-loop plane (seg 4): sequential read
    {
        const _Float16* zp = z + (size_t)R_REL * N_NODES * D;
        half4v v = *(const half4v*)(zp + (size_t)n * D + lane * 4);
        ax += (float)v[0]; ay += (float)v[1];
        az += (float)v[2]; aw += (float)v[3];
    }

    float4 bv = ((const float4*)bias)[lane];
    float4 o;
    o.x = fmaxf(ax + bv.x, 0.f);
    o.y = fmaxf(ay + bv.y, 0.f);
    o.z = fmaxf(az + bv.z, 0.f);
    o.w = fmaxf(aw + bv.w, 0.f);
    ((float4*)(out + (size_t)n * D))[lane] = o;
}

extern "C" void kernel_launch(void* const* d_in, const int* in_sizes, int n_in,
                              void* d_out, int out_size, void* d_ws, size_t ws_size,
                              hipStream_t stream)
{
    const float* x      = (const float*)d_in[0];
    const int*   src    = (const int*)d_in[1];
    const int*   dst    = (const int*)d_in[2];
    const float* rel_w  = (const float*)d_in[3];
    const float* loop_w = (const float*)d_in[4];
    const float* bias   = (const float*)d_in[5];
    float* out = (float*)d_out;

    // ws layout: cnt[M_SEG] | epool[M_SEG*CAP] | bh (fp16) | align | z (fp16)
    // total ~ 1.6 + 25.6 + 0.33 + 128 MB = 155.5 MB (ws evidence: >= 206 MB)
    int* cnt   = (int*)d_ws;
    int* epool = cnt + M_SEG;
    _Float16* bh = (_Float16*)(epool + (size_t)M_SEG * CAP);
    size_t zoff = ((size_t)M_SEG * 4 + (size_t)M_SEG * CAP * 4 +
                   (size_t)BCONV_N * 2 + 255) & ~(size_t)255;
    _Float16* z = (_Float16*)((char*)d_ws + zoff);

    hipMemsetAsync(cnt, 0, (size_t)M_SEG * sizeof(int), stream);
    prep_kernel<<<EB + BB, 256, 0, stream>>>(src, dst, rel_w, loop_w,
                                             cnt, epool, bh);

    const int gblocks = (N_NODES + 63) / 64;
    gemmz_kernel<<<gblocks, 256, 0, stream>>>(x, bh, z);

    const int ablocks = (N_NODES * 32 + 255) / 256;
    aggk_kernel<<<ablocks, 256, 0, stream>>>(z, cnt, epool, bias, out);
}

// Round 10
// 238.241 us; speedup vs baseline: 1.7986x; 1.0949x over previous
//
#include <hip/hip_runtime.h>

#define N_NODES 100000
#define D 128
#define R_REL 4
#define E_EDGES 150000
#define M_SEG (R_REL * N_NODES)          // 400000 segments (r, dst)
#define NSEG 5                           // 4 relations + self-loop
#define CAP 16                           // fixed bin capacity per segment
#define PLANE ((size_t)N_NODES * D)      // fp16 elements per plane

typedef _Float16 half8v __attribute__((ext_vector_type(8)));
typedef float f32x4 __attribute__((ext_vector_type(4)));

#define EB ((R_REL * E_EDGES + 255) / 256)       // edge-binning blocks
#define BCONV_N (NSEG * 4 * 8 * 64 * 8)          // W fragment elements
#define BB ((BCONV_N + 255) / 256)               // W-convert blocks
#define XB ((N_NODES * 16 + 255) / 256)          // x-convert blocks

__device__ __forceinline__ void gload_lds16(const void* g, void* l) {
    __builtin_amdgcn_global_load_lds(
        (const __attribute__((address_space(1))) unsigned int*)g,
        (__attribute__((address_space(3))) unsigned int*)l, 16, 0, 0);
}

// ---------------------------------------------------------------------------
// Prep (3 block ranges):
//  [0,EB)       one-pass edge binning: cnt[sid]++, epool[sid*CAP+pos]=src
//  [EB,EB+BB)   W -> fp16 in MFMA B-frag order [seg][ks][t][lane][8]
//  [EB+BB,..)   x -> fp16 plane (zall seg 4), 16B chunks PRE-SWIZZLED by
//               chunk^(n&7) so gemm's global_load_lds is a linear copy.
// ---------------------------------------------------------------------------
__global__ __launch_bounds__(256) void prep_kernel(
    const int* __restrict__ src_idx, const int* __restrict__ dst_idx,
    const float* __restrict__ rel_w, const float* __restrict__ loop_w,
    const float* __restrict__ x,
    int* __restrict__ cnt, int* __restrict__ epool,
    _Float16* __restrict__ bh, _Float16* __restrict__ zall)
{
    if (blockIdx.x < EB) {
        int idx = blockIdx.x * 256 + threadIdx.x;
        if (idx >= R_REL * E_EDGES) return;
        int r = idx / E_EDGES;
        int i = r * N_NODES + dst_idx[idx];
        int pos = atomicAdd(&cnt[i], 1);
        if (pos < CAP) epool[(size_t)i * CAP + pos] = src_idx[idx];
    } else if (blockIdx.x < EB + BB) {
        int idx = (blockIdx.x - EB) * 256 + threadIdx.x;
        if (idx >= BCONV_N) return;
        int j   = idx & 7;
        int l   = (idx >> 3) & 63;
        int t   = (idx >> 9) & 7;
        int ks  = (idx >> 12) & 3;
        int seg = idx >> 14;
        int k   = ks * 32 + (l >> 4) * 8 + j;
        int col = t * 16 + (l & 15);
        float v = (seg < R_REL) ? rel_w[((size_t)seg * D + k) * D + col]
                                : loop_w[(size_t)k * D + col];
        bh[idx] = (_Float16)v;
    } else {
        int f = (blockIdx.x - EB - BB) * 256 + threadIdx.x;
        if (f >= N_NODES * 16) return;
        int n = f >> 4;
        int c = f & 15;                 // logical 16B chunk (8 fp16)
        const float4* x4 = (const float4*)x;
        float4 a = x4[(size_t)n * 32 + c * 2];
        float4 b = x4[(size_t)n * 32 + c * 2 + 1];
        half8v h = {(_Float16)a.x, (_Float16)a.y, (_Float16)a.z, (_Float16)a.w,
                    (_Float16)b.x, (_Float16)b.y, (_Float16)b.z, (_Float16)b.w};
        _Float16* xp = zall + (size_t)R_REL * PLANE;
        *(half8v*)(xp + (size_t)n * D + ((c ^ (n & 7)) * 8)) = h;
    }
}

// ---------------------------------------------------------------------------
// High-TLP aggregation: 16 lanes per (relation,node) segment, 6.4M threads.
// Gather fp16 x rows (25.6 MB, cache-resident), fp32-accumulate, /deg,
// write fp16 agg plane with the same chunk^(n&7) pre-swizzle.
// ---------------------------------------------------------------------------
__global__ __launch_bounds__(256) void aggh_kernel(
    const int* __restrict__ cnt,
    const int* __restrict__ epool,
    _Float16* __restrict__ zall)
{
    int idx = blockIdx.x * 256 + threadIdx.x;
    int sid = idx >> 4;                 // segment id
    int lane = idx & 15;                // logical 16B chunk of the row
    if (sid >= M_SEG) return;
    int n = sid % N_NODES;

    const _Float16* xp = zall + (size_t)R_REL * PLANE;
    int c = cnt[sid];
    int cc = min(c, CAP);
    int4 i4 = ((const int4*)epool)[(size_t)sid * (CAP / 4)];

    int s0 = (0 < cc) ? i4.x : 0;  float m0 = (0 < cc) ? 1.f : 0.f;
    int s1 = (1 < cc) ? i4.y : 0;  float m1 = (1 < cc) ? 1.f : 0.f;
    int s2 = (2 < cc) ? i4.z : 0;  float m2 = (2 < cc) ? 1.f : 0.f;
    int s3 = (3 < cc) ? i4.w : 0;  float m3 = (3 < cc) ? 1.f : 0.f;
    half8v v0 = *(const half8v*)(xp + (size_t)s0 * D + ((lane ^ (s0 & 7)) * 8));
    half8v v1 = *(const half8v*)(xp + (size_t)s1 * D + ((lane ^ (s1 & 7)) * 8));
    half8v v2 = *(const half8v*)(xp + (size_t)s2 * D + ((lane ^ (s2 & 7)) * 8));
    half8v v3 = *(const half8v*)(xp + (size_t)s3 * D + ((lane ^ (s3 & 7)) * 8));

    float s[8];
    #pragma unroll
    for (int e = 0; e < 8; e++)
        s[e] = (float)v0[e] * m0 + (float)v1[e] * m1 +
               (float)v2[e] * m2 + (float)v3[e] * m3;

    for (int j = 4; j < cc; j++) {
        int sj = epool[(size_t)sid * CAP + j];
        half8v v = *(const half8v*)(xp + (size_t)sj * D + ((lane ^ (sj & 7)) * 8));
        #pragma unroll
        for (int e = 0; e < 8; e++) s[e] += (float)v[e];
    }

    float sc = 1.0f / fmaxf((float)c, 1.0f);
    half8v o;
    #pragma unroll
    for (int e = 0; e < 8; e++) o[e] = (_Float16)(s[e] * sc);
    *(half8v*)(zall + (size_t)sid * D + ((lane ^ (n & 7)) * 8)) = o;
}

// ---------------------------------------------------------------------------
// Single-pass fp16 MFMA GEMM over K=640 (5 pre-swizzled planes), fused
// bias+relu epilogue. Block: 64 rows x 128 cols, 256 threads (4 waves).
// Per segment: global_load_lds (linear copy = swizzled tile), 4 A-frag
// ds_reads, 32 MFMAs/wave accumulating across segments. Epilogue: acc ->
// LDS (pitch 528B) -> coalesced float4 stores.
// ---------------------------------------------------------------------------
__global__ __launch_bounds__(256) void gemm_kernel(
    const _Float16* __restrict__ zall,
    const _Float16* __restrict__ bh,
    const float* __restrict__ bias,
    float* __restrict__ out)
{
    __shared__ __align__(16) char lds[64 * 528];    // 33.8 KB (stage 16 KB)

    int tid = threadIdx.x;
    int w = tid >> 6;                   // wave 0..3
    int l = tid & 63;                   // lane
    int n0 = blockIdx.x * 64;

    f32x4 acc[8];
    #pragma unroll
    for (int t = 0; t < 8; t++) acc[t] = (f32x4){0.f, 0.f, 0.f, 0.f};

    int arow = w * 16 + (l & 15);

    for (int seg = 0; seg < NSEG; seg++) {
        const char* plane = (const char*)(zall + (size_t)seg * PLANE)
                          + (size_t)n0 * 256;
        #pragma unroll
        for (int p = 0; p < 4; p++) {
            int f = p * 256 + tid;
            gload_lds16(plane + f * 16, lds + f * 16);
        }
        __syncthreads();                // drains vmcnt before barrier

        half8v aF[4];
        #pragma unroll
        for (int ks = 0; ks < 4; ks++) {
            int cbyte = (ks * 64 + ((l >> 4) << 4)) ^ ((arow & 7) << 4);
            aF[ks] = *(const half8v*)(lds + arow * 256 + cbyte);
        }
        #pragma unroll
        for (int ks = 0; ks < 4; ks++) {
            size_t fb = ((((size_t)seg * 4 + ks) * 8) * 64 + l) * 8;
            #pragma unroll
            for (int t = 0; t < 8; t++) {
                half8v bF = *(const half8v*)(bh + fb + (size_t)t * 512);
                acc[t] = __builtin_amdgcn_mfma_f32_16x16x32_f16(aF[ks], bF, acc[t], 0, 0, 0);
            }
        }
        __syncthreads();                // protect LDS before next stage
    }

    // ---- epilogue: bias + relu in regs, LDS transpose, coalesced store ----
    int cl = l & 15;
    int lrow0 = w * 16 + ((l >> 4) << 2);
    #pragma unroll
    for (int t = 0; t < 8; t++) {
        float bv = bias[t * 16 + cl];
        #pragma unroll
        for (int reg = 0; reg < 4; reg++) {
            float v = fmaxf(acc[t][reg] + bv, 0.f);
            ((float*)(lds + (lrow0 + reg) * 528))[t * 16 + cl] = v;
        }
    }
    __syncthreads();
    #pragma unroll
    for (int p = 0; p < 8; p++) {
        int f = p * 256 + tid;
        int row = f >> 5;
        int s = f & 31;
        float4 rv = *(const float4*)(lds + row * 528 + s * 16);
        int n = n0 + row;
        if (n < N_NODES)
            *(float4*)((char*)(out + (size_t)n * D) + s * 16) = rv;
    }
}

extern "C" void kernel_launch(void* const* d_in, const int* in_sizes, int n_in,
                              void* d_out, int out_size, void* d_ws, size_t ws_size,
                              hipStream_t stream)
{
    const float* x      = (const float*)d_in[0];
    const int*   src    = (const int*)d_in[1];
    const int*   dst    = (const int*)d_in[2];
    const float* rel_w  = (const float*)d_in[3];
    const float* loop_w = (const float*)d_in[4];
    const float* bias   = (const float*)d_in[5];
    float* out = (float*)d_out;

    // ws: cnt[M_SEG] | epool[M_SEG*CAP] | bh fp16 | align | zall = 5 fp16
    // planes (agg0..agg3, xh). Total ~155.9 MB (ws evidence: >= 206 MB).
    int* cnt   = (int*)d_ws;
    int* epool = cnt + M_SEG;
    _Float16* bh = (_Float16*)(epool + (size_t)M_SEG * CAP);
    size_t zoff = ((size_t)M_SEG * 4 + (size_t)M_SEG * CAP * 4 +
                   (size_t)BCONV_N * 2 + 255) & ~(size_t)255;
    _Float16* zall = (_Float16*)((char*)d_ws + zoff);

    hipMemsetAsync(cnt, 0, (size_t)M_SEG * sizeof(int), stream);
    prep_kernel<<<EB + BB + XB, 256, 0, stream>>>(src, dst, rel_w, loop_w, x,
                                                  cnt, epool, bh, zall);

    const int ablocks = (M_SEG * 16) / 256;         // 25000
    aggh_kernel<<<ablocks, 256, 0, stream>>>(cnt, epool, zall);

    const int gblocks = (N_NODES + 63) / 64;        // 1563
    gemm_kernel<<<gblocks, 256, 0, stream>>>(zall, bh, bias, out);
}